// Round 1
// baseline (469.344 us; speedup 1.0000x reference)
//
#include <hip/hip_runtime.h>
#include <math.h>

#define B_ 256
#define T_ 2048
#define N_ 17

__device__ __forceinline__ float rlf(float v, int i) {
    return __int_as_float(__builtin_amdgcn_readlane(__float_as_int(v), i));
}

// ---------------- kernel 1: build 17x17 log-transition matrix ----------------
__global__ __launch_bounds__(256) void build_trans_k(
    const float* __restrict__ hiddens, const float* __restrict__ p_in,
    const float* __restrict__ p_cross, const float* __restrict__ p_out,
    const float* __restrict__ p_to_out, const float* __restrict__ p_from_out,
    const float* __restrict__ w_attn, const float* __restrict__ b_attn,
    float* __restrict__ trans)
{
    __shared__ float partial[32][8];
    __shared__ float att[8][4];
    int tid = threadIdx.x;
    int pair = tid >> 3, sub = tid & 7;
    int e = pair >> 2, a = pair & 3;
    float acc = 0.f;
    for (int h = sub; h < 768; h += 8)
        acc += hiddens[e*768 + h] * w_attn[h*4 + a];
    partial[pair][sub] = acc;
    __syncthreads();
    if (tid < 32) {
        float s = 0.f;
        for (int k2 = 0; k2 < 8; ++k2) s += partial[tid][k2];
        att[tid>>2][tid&3] = s + b_attn[tid&3];
    }
    __syncthreads();
    if (tid == 0) {
        float t1[8][4], t2[8][4];
        // softmax over E (axis 0)
        for (int a2 = 0; a2 < 4; ++a2) {
            float m = -1e30f;
            for (int e2 = 0; e2 < 8; ++e2) m = fmaxf(m, att[e2][a2]);
            float s = 0.f;
            for (int e2 = 0; e2 < 8; ++e2) { t1[e2][a2] = expf(att[e2][a2] - m); s += t1[e2][a2]; }
            for (int e2 = 0; e2 < 8; ++e2) t1[e2][a2] /= s;
        }
        // softmax over A (axis -1) of t1*10
        for (int e2 = 0; e2 < 8; ++e2) {
            float m = -1e30f;
            for (int a2 = 0; a2 < 4; ++a2) m = fmaxf(m, t1[e2][a2]*10.f);
            float s = 0.f;
            for (int a2 = 0; a2 < 4; ++a2) { t2[e2][a2] = expf(t1[e2][a2]*10.f - m); s += t2[e2][a2]; }
            for (int a2 = 0; a2 < 4; ++a2) t2[e2][a2] /= s;
        }
        trans[0] = p_out[0];
        for (int c = 0; c < 16; ++c) trans[0*N_ + 1 + c] = p_from_out[c & 1];
        for (int r = 0; r < 16; ++r) trans[(1+r)*N_ + 0] = p_to_out[r & 1];
        for (int eb = 0; eb < 8; ++eb)
        for (int r = 0; r < 2; ++r)
        for (int ec = 0; ec < 8; ++ec)
        for (int c = 0; c < 2; ++c) {
            float v;
            if (eb == ec) {
                v = 0.f;
                for (int a2 = 0; a2 < 4; ++a2) v += p_in[a2*4 + r*2 + c] * t2[eb][a2];
                v *= 0.25f;
            } else v = p_cross[r*2 + c];
            trans[(1 + eb*2 + r)*N_ + (1 + ec*2 + c)] = v;
        }
    }
}

// ---------------- kernel 2: forward recursion, one wave per batch ----------------
// Scaled linear domain: w_j ~ exp(alpha_j - offset). Per step:
//   acc_j = sum_i w_i * exp(trans[i][j])   (17 FMA via readlane-SGPR broadcast)
//   w'_j  = acc_j * exp(emit_j) * 2^{-pend}   (pend = pending power-of-2 renorm)
// Scale bookkeeping is pure integer (exponent-field extraction) — no logs in loop.
__global__ __launch_bounds__(64) void forward_k(
    const float* __restrict__ inputs, const int* __restrict__ mask,
    const float* __restrict__ trans, float* __restrict__ denom)
{
    const int b = blockIdx.x;
    const int lane = threadIdx.x;
    const bool active = lane < N_;
    const int j = active ? lane : 0;

    float Ecol[N_];
    #pragma unroll
    for (int i = 0; i < N_; ++i)
        Ecol[i] = active ? expf(trans[i*N_ + j]) : 0.f;

    const float* ep = inputs + (size_t)b * T_ * N_ + j;
    const int*   mp = mask + (size_t)b * T_;

    float a0 = active ? ep[0] : -1e30f;
    float m0 = rlf(a0, 0);
    #pragma unroll
    for (int i = 1; i < N_; ++i) m0 = fmaxf(m0, rlf(a0, i));
    float w = active ? exp2f((a0 - m0) * 1.44269504088896340736f) : 0.f;

    float s_w[N_];
    #pragma unroll
    for (int i = 0; i < N_; ++i) s_w[i] = rlf(w, i);
    unsigned mxb = __float_as_uint(s_w[0]);
    #pragma unroll
    for (int i = 1; i < N_; ++i) { unsigned bi = __float_as_uint(s_w[i]); mxb = bi > mxb ? bi : mxb; }
    int pend = (int)(mxb >> 23) - 127;
    int K = 0;
    float sc = __uint_as_float((unsigned)(127 - pend) << 23);

    // rotating 16-deep prefetch of emissions + mask
    float ebuf[16]; int mbuf[16];
    #pragma unroll
    for (int p = 0; p < 16; ++p) {
        ebuf[p] = ep[(size_t)(1 + p) * N_];
        mbuf[p] = mp[1 + p];
    }

    #pragma unroll 16
    for (int t = 0; t < T_; ++t) {          // step time = t+1; iter t==T_-1 is masked pad
        const int slot = t & 15;
        float ev = ebuf[slot];
        int   mv = mbuf[slot];
        int tn = t + 17; if (tn > T_ - 1) tn = T_ - 1;
        ebuf[slot] = ep[(size_t)tn * N_];
        mbuf[slot] = mp[tn];

        float e = exp2f(ev * 1.44269504088896340736f) * sc;
        float acc0 = s_w[0]*Ecol[0];
        float acc1 = s_w[1]*Ecol[1];
        float acc2 = s_w[2]*Ecol[2];
        float acc3 = s_w[3]*Ecol[3];
        #pragma unroll
        for (int i = 4; i < 16; i += 4) {
            acc0 = fmaf(s_w[i+0], Ecol[i+0], acc0);
            acc1 = fmaf(s_w[i+1], Ecol[i+1], acc1);
            acc2 = fmaf(s_w[i+2], Ecol[i+2], acc2);
            acc3 = fmaf(s_w[i+3], Ecol[i+3], acc3);
        }
        acc0 = fmaf(s_w[16], Ecol[16], acc0);
        float accs = (acc0 + acc1) + (acc2 + acc3);
        float wn = accs * e;

        int mvu = __builtin_amdgcn_readfirstlane(mv);
        bool upd = (mvu > 0) && (t < T_ - 1);
        w = upd ? wn : w;

        #pragma unroll
        for (int i = 0; i < N_; ++i) s_w[i] = rlf(w, i);
        unsigned mx2 = __float_as_uint(s_w[0]);
        #pragma unroll
        for (int i = 1; i < N_; ++i) { unsigned bi = __float_as_uint(s_w[i]); mx2 = bi > mx2 ? bi : mx2; }
        int knew = (int)(mx2 >> 23) - 127;
        K    = upd ? K + pend : K;
        pend = upd ? knew : pend;
        sc = __uint_as_float((unsigned)(127 - pend) << 23);
    }

    float s = w;
    #pragma unroll
    for (int off = 32; off > 0; off >>= 1) s += __shfl_xor(s, off, 64);
    if (lane == 0)
        denom[b] = logf(s) + (float)K * 0.69314718055994530942f + m0;
}

// ---------------- kernel 3: numerator score + final reduction ----------------
__global__ __launch_bounds__(256) void numer_k(
    const float* __restrict__ inputs, const int* __restrict__ tags,
    const int* __restrict__ mask, const float* __restrict__ trans,
    const float* __restrict__ denom, float* __restrict__ out)
{
    const int b = blockIdx.x, tid = threadIdx.x;
    const int* tg = tags + (size_t)b * T_;
    const int* mp = mask + (size_t)b * T_;
    const float* ip = inputs + (size_t)b * T_ * N_;
    float tsum = 0.f, esum = 0.f; int msum = 0;
    for (int t = tid; t < T_ - 1; t += 256) {
        int g = tg[t], g2 = tg[t+1];
        int m1 = mp[t], m2 = mp[t+1];
        tsum += (m2 > 0) ? trans[g*N_ + g2] : 0.f;
        esum += (m1 > 0) ? ip[(size_t)t*N_ + g] : 0.f;
        msum += (m1 > 0) ? 1 : 0;
    }
    if (tid == 0) msum += (mp[T_-1] > 0) ? 1 : 0;
    #pragma unroll
    for (int off = 32; off > 0; off >>= 1) {
        tsum += __shfl_xor(tsum, off, 64);
        esum += __shfl_xor(esum, off, 64);
        msum += __shfl_xor(msum, off, 64);
    }
    __shared__ float r0[4], r1[4]; __shared__ int r2[4];
    int wid = tid >> 6;
    if ((tid & 63) == 0) { r0[wid] = tsum; r1[wid] = esum; r2[wid] = msum; }
    __syncthreads();
    if (tid == 0) {
        float ts = r0[0]+r0[1]+r0[2]+r0[3];
        float es = r1[0]+r1[1]+r1[2]+r1[3];
        int   ms = r2[0]+r2[1]+r2[2]+r2[3];
        int lt = tg[ms - 1];
        float le = (mp[T_-1] > 0) ? ip[(size_t)(T_-1)*N_ + lt] : 0.f;
        atomicAdd(out, ts + es + le - denom[b]);
    }
}

extern "C" void kernel_launch(void* const* d_in, const int* in_sizes, int n_in,
                              void* d_out, int out_size, void* d_ws, size_t ws_size,
                              hipStream_t stream)
{
    const float* inputs    = (const float*)d_in[0];
    const int*   tags      = (const int*)  d_in[1];
    const float* hiddens   = (const float*)d_in[2];
    const int*   mask      = (const int*)  d_in[3];
    const float* p_in      = (const float*)d_in[4];
    const float* p_cross   = (const float*)d_in[5];
    const float* p_out     = (const float*)d_in[6];
    const float* p_to_out  = (const float*)d_in[7];
    const float* p_from_out= (const float*)d_in[8];
    const float* w_attn    = (const float*)d_in[9];
    const float* b_attn    = (const float*)d_in[10];
    float* out = (float*)d_out;
    float* ws  = (float*)d_ws;
    float* trans = ws;          // 289 floats
    float* denom = ws + 512;    // 256 floats

    hipMemsetAsync(d_out, 0, sizeof(float), stream);
    hipLaunchKernelGGL(build_trans_k, dim3(1), dim3(256), 0, stream,
                       hiddens, p_in, p_cross, p_out, p_to_out, p_from_out,
                       w_attn, b_attn, trans);
    hipLaunchKernelGGL(forward_k, dim3(B_), dim3(64), 0, stream,
                       inputs, mask, trans, denom);
    hipLaunchKernelGGL(numer_k, dim3(B_), dim3(256), 0, stream,
                       inputs, tags, mask, trans, denom, out);
}

// Round 2
// 329.662 us; speedup vs baseline: 1.4237x; 1.4237x over previous
//
#include <hip/hip_runtime.h>
#include <math.h>

#define B_ 256
#define T_ 2048
#define N_ 17

typedef float v2f __attribute__((ext_vector_type(2)));

__device__ __forceinline__ float rlf(float v, int i) {
    return __int_as_float(__builtin_amdgcn_readlane(__float_as_int(v), i));
}

// ---------------- kernel 1: build 17x17 log-transition matrix ----------------
__global__ __launch_bounds__(256) void build_trans_k(
    const float* __restrict__ hiddens, const float* __restrict__ p_in,
    const float* __restrict__ p_cross, const float* __restrict__ p_out,
    const float* __restrict__ p_to_out, const float* __restrict__ p_from_out,
    const float* __restrict__ w_attn, const float* __restrict__ b_attn,
    float* __restrict__ trans)
{
    __shared__ float partial[32][8];
    __shared__ float att[8][4];
    int tid = threadIdx.x;
    int pair = tid >> 3, sub = tid & 7;
    int e = pair >> 2, a = pair & 3;
    float acc = 0.f;
    for (int h = sub; h < 768; h += 8)
        acc += hiddens[e*768 + h] * w_attn[h*4 + a];
    partial[pair][sub] = acc;
    __syncthreads();
    if (tid < 32) {
        float s = 0.f;
        for (int k2 = 0; k2 < 8; ++k2) s += partial[tid][k2];
        att[tid>>2][tid&3] = s + b_attn[tid&3];
    }
    __syncthreads();
    if (tid == 0) {
        float t1[8][4], t2[8][4];
        for (int a2 = 0; a2 < 4; ++a2) {
            float m = -1e30f;
            for (int e2 = 0; e2 < 8; ++e2) m = fmaxf(m, att[e2][a2]);
            float s = 0.f;
            for (int e2 = 0; e2 < 8; ++e2) { t1[e2][a2] = expf(att[e2][a2] - m); s += t1[e2][a2]; }
            for (int e2 = 0; e2 < 8; ++e2) t1[e2][a2] /= s;
        }
        for (int e2 = 0; e2 < 8; ++e2) {
            float m = -1e30f;
            for (int a2 = 0; a2 < 4; ++a2) m = fmaxf(m, t1[e2][a2]*10.f);
            float s = 0.f;
            for (int a2 = 0; a2 < 4; ++a2) { t2[e2][a2] = expf(t1[e2][a2]*10.f - m); s += t2[e2][a2]; }
            for (int a2 = 0; a2 < 4; ++a2) t2[e2][a2] /= s;
        }
        trans[0] = p_out[0];
        for (int c = 0; c < 16; ++c) trans[0*N_ + 1 + c] = p_from_out[c & 1];
        for (int r = 0; r < 16; ++r) trans[(1+r)*N_ + 0] = p_to_out[r & 1];
        for (int eb = 0; eb < 8; ++eb)
        for (int r = 0; r < 2; ++r)
        for (int ec = 0; ec < 8; ++ec)
        for (int c = 0; c < 2; ++c) {
            float v;
            if (eb == ec) {
                v = 0.f;
                for (int a2 = 0; a2 < 4; ++a2) v += p_in[a2*4 + r*2 + c] * t2[eb][a2];
                v *= 0.25f;
            } else v = p_cross[r*2 + c];
            trans[(1 + eb*2 + r)*N_ + (1 + ec*2 + c)] = v;
        }
    }
}

// ---------------- kernel 2: forward recursion, one wave per batch ----------------
// Scaled linear domain, register-resident 16-step prefetch ring, rescale every
// 8 steps (SALU max tree off the vector critical path), packed-f32 FMA dot.
#define LOG2E 1.44269504088896340736f

// one recursion step; SV = the 17 readlaned state values (SGPRs)
#define STEP_BODY(EV, MV, RESCALE)                                             \
    {                                                                          \
        float sv[N_];                                                          \
        _Pragma("unroll")                                                      \
        for (int i = 0; i < N_; ++i) sv[i] = rlf(w, i);                        \
        float e = exp2f((EV) * LOG2E);                                         \
        v2f sp[9];                                                             \
        _Pragma("unroll")                                                      \
        for (int k2 = 0; k2 < 8; ++k2) { sp[k2].x = sv[2*k2]; sp[k2].y = sv[2*k2+1]; } \
        sp[8].x = sv[16]; sp[8].y = 0.f;                                       \
        v2f A = sp[0]*Ec[0];                                                   \
        v2f Bv = sp[1]*Ec[1];                                                  \
        A  = sp[2]*Ec[2] + A;  Bv = sp[3]*Ec[3] + Bv;                          \
        A  = sp[4]*Ec[4] + A;  Bv = sp[5]*Ec[5] + Bv;                          \
        A  = sp[6]*Ec[6] + A;  Bv = sp[7]*Ec[7] + Bv;                          \
        A  = sp[8]*Ec[8] + A;                                                  \
        v2f S2 = A + Bv;                                                       \
        float wn = (S2.x + S2.y) * e;                                          \
        bool upd = __builtin_amdgcn_readfirstlane(MV) > 0;                     \
        w = upd ? wn : w;                                                      \
        if (RESCALE) {                                                         \
            unsigned mx = __float_as_uint(sv[0]);                              \
            _Pragma("unroll")                                                  \
            for (int i = 1; i < N_; ++i) {                                     \
                unsigned bi = __float_as_uint(sv[i]);                          \
                mx = bi > mx ? bi : mx;                                        \
            }                                                                  \
            int me = (int)(mx >> 23) - 127;                                    \
            float sc = __uint_as_float((unsigned)(127 - me) << 23);            \
            w *= sc;                                                           \
            K += me;                                                           \
        }                                                                      \
    }

__global__ __launch_bounds__(64, 1) void forward_k(
    const float* __restrict__ inputs, const int* __restrict__ mask,
    const float* __restrict__ trans, float* __restrict__ denom)
{
    const int b = blockIdx.x;
    const int lane = threadIdx.x;
    const bool active = lane < N_;
    const int j = active ? lane : 0;

    // E columns as packed pairs over i (state padded 17 -> 18 with zeros)
    v2f Ec[9];
    #pragma unroll
    for (int k = 0; k < 9; ++k) {
        int i0 = 2*k, i1 = 2*k + 1;
        Ec[k].x = active ? expf(trans[i0*N_ + j]) : 0.f;
        Ec[k].y = (active && i1 < N_) ? expf(trans[i1*N_ + j]) : 0.f;
    }

    const float* ep = inputs + (size_t)b * T_ * N_ + j;
    const int*   mp = mask + (size_t)b * T_;

    float a0 = active ? ep[0] : -1e30f;
    float m0 = rlf(a0, 0);
    #pragma unroll
    for (int i = 1; i < N_; ++i) m0 = fmaxf(m0, rlf(a0, i));
    float w = active ? exp2f((a0 - m0) * LOG2E) : 0.f;
    int K = 0;

    // 16-step register-resident prefetch ring (steps st = 1..2047 use slot (st-1)&15)
    float ebuf[16]; int mbuf[16];
    #pragma unroll
    for (int p = 0; p < 16; ++p) {
        ebuf[p] = ep[(size_t)(1 + p) * N_];
        mbuf[p] = mp[1 + p];
    }

    // main: 127 iters x 16 steps = steps 1..2032; rescale after slots 7 and 15
    for (int it = 0; it < 127; ++it) {
        const int st0 = 16*it + 1;
        #pragma unroll
        for (int v = 0; v < 16; ++v) {
            float ev = ebuf[v];
            int   mv = mbuf[v];
            int stn = st0 + v + 16;
            if (stn > T_ - 1) stn = T_ - 1;     // only triggers at st=2032
            ebuf[v] = ep[(size_t)stn * N_];
            mbuf[v] = mp[stn];
            STEP_BODY(ev, mv, (v == 7 || v == 15))
        }
    }

    // epilogue: steps 2033..2047 (slots 0..14), no refills; rescale after slot 7
    #pragma unroll
    for (int v = 0; v < 15; ++v) {
        float ev = ebuf[v];
        int   mv = mbuf[v];
        STEP_BODY(ev, mv, (v == 7))
    }

    float s = w;
    #pragma unroll
    for (int off = 32; off > 0; off >>= 1) s += __shfl_xor(s, off, 64);
    if (lane == 0)
        denom[b] = logf(s) + (float)K * 0.69314718055994530942f + m0;
}

// ---------------- kernel 3: numerator score + final reduction ----------------
__global__ __launch_bounds__(256) void numer_k(
    const float* __restrict__ inputs, const int* __restrict__ tags,
    const int* __restrict__ mask, const float* __restrict__ trans,
    const float* __restrict__ denom, float* __restrict__ out)
{
    const int b = blockIdx.x, tid = threadIdx.x;
    const int* tg = tags + (size_t)b * T_;
    const int* mp = mask + (size_t)b * T_;
    const float* ip = inputs + (size_t)b * T_ * N_;
    float tsum = 0.f, esum = 0.f; int msum = 0;
    for (int t = tid; t < T_ - 1; t += 256) {
        int g = tg[t], g2 = tg[t+1];
        int m1 = mp[t], m2 = mp[t+1];
        tsum += (m2 > 0) ? trans[g*N_ + g2] : 0.f;
        esum += (m1 > 0) ? ip[(size_t)t*N_ + g] : 0.f;
        msum += (m1 > 0) ? 1 : 0;
    }
    if (tid == 0) msum += (mp[T_-1] > 0) ? 1 : 0;
    #pragma unroll
    for (int off = 32; off > 0; off >>= 1) {
        tsum += __shfl_xor(tsum, off, 64);
        esum += __shfl_xor(esum, off, 64);
        msum += __shfl_xor(msum, off, 64);
    }
    __shared__ float r0[4], r1[4]; __shared__ int r2[4];
    int wid = tid >> 6;
    if ((tid & 63) == 0) { r0[wid] = tsum; r1[wid] = esum; r2[wid] = msum; }
    __syncthreads();
    if (tid == 0) {
        float ts = r0[0]+r0[1]+r0[2]+r0[3];
        float es = r1[0]+r1[1]+r1[2]+r1[3];
        int   ms = r2[0]+r2[1]+r2[2]+r2[3];
        int lt = tg[ms - 1];
        float le = (mp[T_-1] > 0) ? ip[(size_t)(T_-1)*N_ + lt] : 0.f;
        atomicAdd(out, ts + es + le - denom[b]);
    }
}

extern "C" void kernel_launch(void* const* d_in, const int* in_sizes, int n_in,
                              void* d_out, int out_size, void* d_ws, size_t ws_size,
                              hipStream_t stream)
{
    const float* inputs    = (const float*)d_in[0];
    const int*   tags      = (const int*)  d_in[1];
    const float* hiddens   = (const float*)d_in[2];
    const int*   mask      = (const int*)  d_in[3];
    const float* p_in      = (const float*)d_in[4];
    const float* p_cross   = (const float*)d_in[5];
    const float* p_out     = (const float*)d_in[6];
    const float* p_to_out  = (const float*)d_in[7];
    const float* p_from_out= (const float*)d_in[8];
    const float* w_attn    = (const float*)d_in[9];
    const float* b_attn    = (const float*)d_in[10];
    float* out = (float*)d_out;
    float* ws  = (float*)d_ws;
    float* trans = ws;          // 289 floats
    float* denom = ws + 512;    // 256 floats

    hipMemsetAsync(d_out, 0, sizeof(float), stream);
    hipLaunchKernelGGL(build_trans_k, dim3(1), dim3(256), 0, stream,
                       hiddens, p_in, p_cross, p_out, p_to_out, p_from_out,
                       w_attn, b_attn, trans);
    hipLaunchKernelGGL(forward_k, dim3(B_), dim3(64), 0, stream,
                       inputs, mask, trans, denom);
    hipLaunchKernelGGL(numer_k, dim3(B_), dim3(256), 0, stream,
                       inputs, tags, mask, trans, denom, out);
}

// Round 3
// 192.655 us; speedup vs baseline: 2.4362x; 1.7111x over previous
//
#include <hip/hip_runtime.h>
#include <math.h>

#define B_ 256
#define T_ 2048
#define N_ 17
#define CHUNKS 16
#define CLEN 128
#define LOG2E 1.44269504088896340736f
#define LN2   0.69314718055994530942f

typedef short bf16x8 __attribute__((ext_vector_type(8)));
typedef float f32x16 __attribute__((ext_vector_type(16)));

__device__ __forceinline__ float rlf(float v, int i) {
    return __int_as_float(__builtin_amdgcn_readlane(__float_as_int(v), i));
}
__device__ __forceinline__ float fexp2(float x) {
    float r;
    asm("v_exp_f32 %0, %1" : "=v"(r) : "v"(x));
    return r;
}
// pack two f32 into bf16x2 (truncation — products are positive, bias negligible)
__device__ __forceinline__ unsigned pack_bf16(float lo, float hi) {
    return __builtin_amdgcn_perm(__float_as_uint(hi), __float_as_uint(lo), 0x07060302u);
}

// ---------------- kernel 1: build 17x17 log-transition matrix ----------------
__global__ __launch_bounds__(256) void build_trans_k(
    const float* __restrict__ hiddens, const float* __restrict__ p_in,
    const float* __restrict__ p_cross, const float* __restrict__ p_out,
    const float* __restrict__ p_to_out, const float* __restrict__ p_from_out,
    const float* __restrict__ w_attn, const float* __restrict__ b_attn,
    float* __restrict__ trans)
{
    __shared__ float partial[32][8];
    __shared__ float att[8][4];
    int tid = threadIdx.x;
    int pair = tid >> 3, sub = tid & 7;
    int e = pair >> 2, a = pair & 3;
    float acc = 0.f;
    for (int h = sub; h < 768; h += 8)
        acc += hiddens[e*768 + h] * w_attn[h*4 + a];
    partial[pair][sub] = acc;
    __syncthreads();
    if (tid < 32) {
        float s = 0.f;
        for (int k2 = 0; k2 < 8; ++k2) s += partial[tid][k2];
        att[tid>>2][tid&3] = s + b_attn[tid&3];
    }
    __syncthreads();
    if (tid == 0) {
        float t1[8][4], t2[8][4];
        for (int a2 = 0; a2 < 4; ++a2) {
            float m = -1e30f;
            for (int e2 = 0; e2 < 8; ++e2) m = fmaxf(m, att[e2][a2]);
            float s = 0.f;
            for (int e2 = 0; e2 < 8; ++e2) { t1[e2][a2] = expf(att[e2][a2] - m); s += t1[e2][a2]; }
            for (int e2 = 0; e2 < 8; ++e2) t1[e2][a2] /= s;
        }
        for (int e2 = 0; e2 < 8; ++e2) {
            float m = -1e30f;
            for (int a2 = 0; a2 < 4; ++a2) m = fmaxf(m, t1[e2][a2]*10.f);
            float s = 0.f;
            for (int a2 = 0; a2 < 4; ++a2) { t2[e2][a2] = expf(t1[e2][a2]*10.f - m); s += t2[e2][a2]; }
            for (int a2 = 0; a2 < 4; ++a2) t2[e2][a2] /= s;
        }
        trans[0] = p_out[0];
        for (int c = 0; c < 16; ++c) trans[0*N_ + 1 + c] = p_from_out[c & 1];
        for (int r = 0; r < 16; ++r) trans[(1+r)*N_ + 0] = p_to_out[r & 1];
        for (int eb = 0; eb < 8; ++eb)
        for (int r = 0; r < 2; ++r)
        for (int ec = 0; ec < 8; ++ec)
        for (int c = 0; c < 2; ++c) {
            float v;
            if (eb == ec) {
                v = 0.f;
                for (int a2 = 0; a2 < 4; ++a2) v += p_in[a2*4 + r*2 + c] * t2[eb][a2];
                v *= 0.25f;
            } else v = p_cross[r*2 + c];
            trans[(1 + eb*2 + r)*N_ + (1 + ec*2 + c)] = v;
        }
    }
}

// ---------------- kernel 2: phase A — per-chunk product matrices via MFMA ----
// Track Q = P^T: Q <- M_t^T * Q, M_t^T = diag(e_t) * T~^T.
// Q lives in MFMA C-layout (32x32): col = lane&31, row = (reg&3)+8*(reg>>2)+4*(lane>>5).
// A operand (M_t^T, bf16): m = lane&31, k = 8*(lane>>5)+j.  B operand (Q, bf16):
// n = lane&31, k = 8*(lane>>5)+j — built from C-layout acc via v_permlane32_swap.
__global__ __launch_bounds__(64, 4) void phaseA_k(
    const float* __restrict__ inputs, const int* __restrict__ mask,
    const float* __restrict__ trans, unsigned short* __restrict__ Qout,
    int* __restrict__ Kout)
{
    const int gid = blockIdx.x;
    const int b = gid >> 4;
    const int c = gid & (CHUNKS - 1);
    const int lane = threadIdx.x & 63;
    const int n = lane & 31;
    const int h = lane >> 5;

    // constant T~^T fragments (f32, scaled by e each step then packed)
    float TA1[8];
    #pragma unroll
    for (int r2 = 0; r2 < 8; ++r2) {
        int k = 8*h + r2;
        TA1[r2] = (n < N_ && k < N_) ? expf(trans[k*N_ + n]) : 0.f;
    }
    float TA2 = (n < N_ && h == 0) ? expf(trans[16*N_ + n]) : 0.f;

    // acc = identity in C-layout
    f32x16 acc;
    #pragma unroll
    for (int r = 0; r < 16; ++r) {
        int R = (r & 3) + 8*(r >> 2) + 4*h;
        acc[r] = (R == n) ? 1.f : 0.f;
    }
    const f32x16 fz = {};

    const int t0 = c * CLEN;
    const float* ep = inputs + (size_t)b*T_*N_ + (n < N_ ? n : N_-1);
    const int*   mp = mask + (size_t)b*T_;

    float re[8]; int rm[8];
    #pragma unroll
    for (int p = 0; p < 8; ++p) {
        int t = t0 + p;
        re[p] = ep[(size_t)t * N_];
        rm[p] = (t == 0) ? 0 : mp[t];
    }

    int K = 0;
    for (int s8 = 0; s8 < CLEN/8; ++s8) {
        #pragma unroll
        for (int u = 0; u < 8; ++u) {
            int s = s8*8 + u;
            float ev = re[u]; int mv = rm[u];
            int tn = t0 + s + 8; tn = tn > T_-1 ? T_-1 : tn;   // clamp (tail refills unused)
            re[u] = ep[(size_t)tn * N_];
            rm[u] = mp[tn];
            if (__builtin_amdgcn_readfirstlane(mv) > 0) {
                float e = fexp2(ev * LOG2E);
                union { unsigned u[4]; bf16x8 v; } a1, a2, b1, b2;
                #pragma unroll
                for (int r2 = 0; r2 < 4; ++r2)
                    a1.u[r2] = pack_bf16(TA1[2*r2]*e, TA1[2*r2+1]*e);
                a2.u[0] = pack_bf16(TA2*e, 0.f);
                a2.u[1] = 0; a2.u[2] = 0; a2.u[3] = 0;
                // B1: k=0..15 of Q from acc regs 0..7 via half-wave swaps
                float sa0=acc[0], sa1=acc[1], sa2=acc[2], sa3=acc[3];
                float sa4=acc[4], sa5=acc[5], sa6=acc[6], sa7=acc[7];
                asm("v_permlane32_swap_b32 %0, %1" : "+v"(sa4), "+v"(sa0));
                asm("v_permlane32_swap_b32 %0, %1" : "+v"(sa5), "+v"(sa1));
                asm("v_permlane32_swap_b32 %0, %1" : "+v"(sa6), "+v"(sa2));
                asm("v_permlane32_swap_b32 %0, %1" : "+v"(sa7), "+v"(sa3));
                b1.u[0] = pack_bf16(sa0, sa1);
                b1.u[1] = pack_bf16(sa2, sa3);
                b1.u[2] = pack_bf16(sa4, sa5);
                b1.u[3] = pack_bf16(sa6, sa7);
                // B2: only k=16 (rows >=17 of Q are identically 0; A kills k>=17)
                unsigned p89 = pack_bf16(acc[8], acc[9]);
                b2.u[0] = (h == 0) ? p89 : 0u;
                b2.u[1] = 0; b2.u[2] = 0; b2.u[3] = 0;
                f32x16 nacc = __builtin_amdgcn_mfma_f32_32x32x16_bf16(a1.v, b1.v, fz, 0, 0, 0);
                nacc = __builtin_amdgcn_mfma_f32_32x32x16_bf16(a2.v, b2.v, nacc, 0, 0, 0);
                acc = nacc;
            }
            if (u == 7) {   // power-of-2 rescale every 8 steps (exact, K-tracked)
                float mx = fmaxf(fmaxf(fmaxf(acc[0],acc[1]),fmaxf(acc[2],acc[3])),
                                 fmaxf(fmaxf(acc[4],acc[5]),fmaxf(acc[6],acc[7])));
                mx = fmaxf(mx, fmaxf(fmaxf(acc[8],acc[9]),fmaxf(acc[10],acc[11])));
                mx = fmaxf(mx, fmaxf(fmaxf(acc[12],acc[13]),fmaxf(acc[14],acc[15])));
                #pragma unroll
                for (int off = 32; off > 0; off >>= 1)
                    mx = fmaxf(mx, __shfl_xor(mx, off, 64));
                int sexp = (int)(__float_as_uint(mx) >> 23) - 127;
                float sc = __uint_as_float((unsigned)(127 - sexp) << 23);
                #pragma unroll
                for (int r = 0; r < 16; ++r) acc[r] *= sc;
                K += sexp;
            }
        }
    }

    // store rows 0..16 of Q as bf16 (row-major, stride 32)
    unsigned short* qb = Qout + (size_t)gid * (N_*32);
    #pragma unroll
    for (int r = 0; r < 16; ++r) {
        int R = (r & 3) + 8*(r >> 2) + 4*h;
        if (R < N_)
            qb[R*32 + n] = (unsigned short)(__float_as_uint(acc[r]) >> 16);
    }
    if (lane == 0) Kout[gid] = K;
}

// ---------------- kernel 3: phase B — combine chunk matrices per batch -------
__global__ __launch_bounds__(64, 1) void combine_k(
    const float* __restrict__ inputs, const unsigned short* __restrict__ Qin,
    const int* __restrict__ Kin, float* __restrict__ denom)
{
    const int b = blockIdx.x;
    const int lane = threadIdx.x & 63;
    const bool active = lane < N_;
    const int j = active ? lane : N_-1;

    const float* ip = inputs + (size_t)b*T_*N_;
    float a0 = active ? ip[j] : -1e30f;
    float m0 = rlf(a0, 0);
    #pragma unroll
    for (int i = 1; i < N_; ++i) m0 = fmaxf(m0, rlf(a0, i));
    float w = active ? fexp2((a0 - m0)*LOG2E) : 0.f;
    int K = 0;

    for (int c = 0; c < CHUNKS; ++c) {
        const unsigned short* qr = Qin + ((size_t)(b*CHUNKS + c))*(N_*32) + j*32;
        uint4 qa = *(const uint4*)qr;          // bf16 cols 0..7 of row j
        uint4 qc4 = *(const uint4*)(qr + 8);   // cols 8..15
        unsigned q16u = qr[16];
        int kc = Kin[b*CHUNKS + c];
        float sv[N_];
        #pragma unroll
        for (int i = 0; i < N_; ++i) sv[i] = rlf(w, i);
        unsigned mxb = __float_as_uint(sv[0]);
        #pragma unroll
        for (int i = 1; i < N_; ++i) { unsigned bi = __float_as_uint(sv[i]); if (bi > mxb) mxb = bi; }
        int me = (int)(mxb >> 23) - 127;
        float sc = __uint_as_float((unsigned)(127 - me) << 23);
        float q[N_];
        q[0]  = __uint_as_float(qa.x << 16);  q[1]  = __uint_as_float(qa.x & 0xFFFF0000u);
        q[2]  = __uint_as_float(qa.y << 16);  q[3]  = __uint_as_float(qa.y & 0xFFFF0000u);
        q[4]  = __uint_as_float(qa.z << 16);  q[5]  = __uint_as_float(qa.z & 0xFFFF0000u);
        q[6]  = __uint_as_float(qa.w << 16);  q[7]  = __uint_as_float(qa.w & 0xFFFF0000u);
        q[8]  = __uint_as_float(qc4.x << 16); q[9]  = __uint_as_float(qc4.x & 0xFFFF0000u);
        q[10] = __uint_as_float(qc4.y << 16); q[11] = __uint_as_float(qc4.y & 0xFFFF0000u);
        q[12] = __uint_as_float(qc4.z << 16); q[13] = __uint_as_float(qc4.z & 0xFFFF0000u);
        q[14] = __uint_as_float(qc4.w << 16); q[15] = __uint_as_float(qc4.w & 0xFFFF0000u);
        q[16] = __uint_as_float(q16u << 16);
        float d0 = sv[0]*q[0], d1 = sv[1]*q[1], d2 = sv[2]*q[2], d3 = sv[3]*q[3];
        #pragma unroll
        for (int i = 4; i < 16; i += 4) {
            d0 = fmaf(sv[i+0], q[i+0], d0);
            d1 = fmaf(sv[i+1], q[i+1], d1);
            d2 = fmaf(sv[i+2], q[i+2], d2);
            d3 = fmaf(sv[i+3], q[i+3], d3);
        }
        d0 = fmaf(sv[16], q[16], d0);
        float nw = ((d0 + d1) + (d2 + d3)) * sc;
        w = active ? nw : 0.f;
        K += me + kc;
    }

    float s = w;
    #pragma unroll
    for (int off = 32; off > 0; off >>= 1) s += __shfl_xor(s, off, 64);
    if (lane == 0)
        denom[b] = logf(s) + (float)K * LN2 + m0;
}

// ---------------- kernel 4: numerator score + final reduction ----------------
__global__ __launch_bounds__(256) void numer_k(
    const float* __restrict__ inputs, const int* __restrict__ tags,
    const int* __restrict__ mask, const float* __restrict__ trans,
    const float* __restrict__ denom, float* __restrict__ out)
{
    const int b = blockIdx.x, tid = threadIdx.x;
    const int* tg = tags + (size_t)b * T_;
    const int* mp = mask + (size_t)b * T_;
    const float* ip = inputs + (size_t)b * T_ * N_;
    float tsum = 0.f, esum = 0.f; int msum = 0;
    for (int t = tid; t < T_ - 1; t += 256) {
        int g = tg[t], g2 = tg[t+1];
        int m1 = mp[t], m2 = mp[t+1];
        tsum += (m2 > 0) ? trans[g*N_ + g2] : 0.f;
        esum += (m1 > 0) ? ip[(size_t)t*N_ + g] : 0.f;
        msum += (m1 > 0) ? 1 : 0;
    }
    if (tid == 0) msum += (mp[T_-1] > 0) ? 1 : 0;
    #pragma unroll
    for (int off = 32; off > 0; off >>= 1) {
        tsum += __shfl_xor(tsum, off, 64);
        esum += __shfl_xor(esum, off, 64);
        msum += __shfl_xor(msum, off, 64);
    }
    __shared__ float r0[4], r1[4]; __shared__ int r2[4];
    int wid = tid >> 6;
    if ((tid & 63) == 0) { r0[wid] = tsum; r1[wid] = esum; r2[wid] = msum; }
    __syncthreads();
    if (tid == 0) {
        float ts = r0[0]+r0[1]+r0[2]+r0[3];
        float es = r1[0]+r1[1]+r1[2]+r1[3];
        int   ms = r2[0]+r2[1]+r2[2]+r2[3];
        int lt = tg[ms - 1];
        float le = (mp[T_-1] > 0) ? ip[(size_t)(T_-1)*N_ + lt] : 0.f;
        atomicAdd(out, ts + es + le - denom[b]);
    }
}

extern "C" void kernel_launch(void* const* d_in, const int* in_sizes, int n_in,
                              void* d_out, int out_size, void* d_ws, size_t ws_size,
                              hipStream_t stream)
{
    const float* inputs    = (const float*)d_in[0];
    const int*   tags      = (const int*)  d_in[1];
    const float* hiddens   = (const float*)d_in[2];
    const int*   mask      = (const int*)  d_in[3];
    const float* p_in      = (const float*)d_in[4];
    const float* p_cross   = (const float*)d_in[5];
    const float* p_out     = (const float*)d_in[6];
    const float* p_to_out  = (const float*)d_in[7];
    const float* p_from_out= (const float*)d_in[8];
    const float* w_attn    = (const float*)d_in[9];
    const float* b_attn    = (const float*)d_in[10];
    float* out = (float*)d_out;
    float* ws  = (float*)d_ws;

    float* trans = ws;                               // 289 f32
    float* denom = ws + 512;                         // 256 f32
    int*   Kbuf  = (int*)(ws + 1024);                // 4096 i32
    unsigned short* Qbuf = (unsigned short*)(ws + 8192);  // 4096*544 bf16 ≈ 4.5 MB

    hipMemsetAsync(d_out, 0, sizeof(float), stream);
    hipLaunchKernelGGL(build_trans_k, dim3(1), dim3(256), 0, stream,
                       hiddens, p_in, p_cross, p_out, p_to_out, p_from_out,
                       w_attn, b_attn, trans);
    hipLaunchKernelGGL(phaseA_k, dim3(B_*CHUNKS), dim3(64), 0, stream,
                       inputs, mask, trans, Qbuf, Kbuf);
    hipLaunchKernelGGL(combine_k, dim3(B_), dim3(64), 0, stream,
                       inputs, Qbuf, Kbuf, denom);
    hipLaunchKernelGGL(numer_k, dim3(B_), dim3(256), 0, stream,
                       inputs, tags, mask, trans, denom, out);
}